// Round 2
// baseline (595.135 us; speedup 1.0000x reference)
//
#include <hip/hip_runtime.h>
#include <cstdint>
#include <cstddef>

// Problem constants (from reference): N=50000, E=800000, IN=512, HID=256, MID=128, OUT=64
#define F_IN  512
#define F_HID 256
#define F_MID 128
#define F_OUT 64

typedef __attribute__((ext_vector_type(8))) short short8;   // 8 x bf16 (4 VGPRs)
typedef __attribute__((ext_vector_type(4))) float floatx4;  // MFMA accumulator

static __device__ __forceinline__ float b2f(ushort u) {
  union { unsigned u; float f; } v; v.u = ((unsigned)u) << 16; return v.f;
}
static __device__ __forceinline__ ushort f2b(float f) {
  union { float f; unsigned u; } v; v.f = f;
  unsigned r = v.u + 0x7fffu + ((v.u >> 16) & 1u);  // round-to-nearest-even
  return (ushort)(r >> 16);
}
static __device__ __forceinline__ uint4 pack8(const float* f) {
  union { ushort u[8]; uint4 v; } r;
#pragma unroll
  for (int t = 0; t < 8; t++) r.u[t] = f2b(f[t]);
  return r.v;
}

// ---------------- CSR build ----------------

__global__ __launch_bounds__(256) void zero_kernel(int* __restrict__ cnt, int n) {
  int i = blockIdx.x * 256 + threadIdx.x;
  if (i < n) cnt[i] = 0;
}

__global__ __launch_bounds__(256) void hist_kernel(const int* __restrict__ dst,
                                                   int* __restrict__ cnt, int e) {
  int i = blockIdx.x * 256 + threadIdx.x;
  if (i < e) atomicAdd(&cnt[dst[i]], 1);
}

__global__ __launch_bounds__(256) void dinv_kernel(const int* __restrict__ cnt,
                                                   float* __restrict__ dinv, int n) {
  int i = blockIdx.x * 256 + threadIdx.x;
  if (i < n) dinv[i] = rsqrtf(1.0f + (float)cnt[i]);  // deg includes self-loop
}

// single-block exclusive scan of cnt -> rp, also zeroes cnt for reuse as fill cursor
__global__ __launch_bounds__(1024) void scan_kernel(int* __restrict__ cnt,
                                                    int* __restrict__ rp, int n) {
  __shared__ int buf[1024];
  int tid = threadIdx.x;
  int carry = 0;
  for (int base = 0; base < n; base += 1024) {
    int i = base + tid;
    int v = (i < n) ? cnt[i] : 0;
    __syncthreads();               // prior tile's buf reads done before overwrite
    buf[tid] = v;
    __syncthreads();
    for (int off = 1; off < 1024; off <<= 1) {
      int t = (tid >= off) ? buf[tid - off] : 0;
      __syncthreads();
      buf[tid] += t;
      __syncthreads();
    }
    int incl = buf[tid];
    int total = buf[1023];
    if (i < n) { rp[i] = carry + incl - v; cnt[i] = 0; }
    carry += total;
  }
  if (tid == 0) rp[n] = carry;     // == E
}

__global__ __launch_bounds__(256) void fill_kernel(const int* __restrict__ src,
                                                   const int* __restrict__ dst,
                                                   const int* __restrict__ rp,
                                                   int* __restrict__ cur,
                                                   int* __restrict__ srcs, int e) {
  int i = blockIdx.x * 256 + threadIdx.x;
  if (i < e) {
    int d = dst[i];
    int p = rp[d] + atomicAdd(&cur[d], 1);
    srcs[p] = src[i];
  }
}

// W (f32, [K][F]) -> WT (bf16, [F][K])
__global__ __launch_bounds__(256) void transpose_kernel(const float* __restrict__ W,
                                                        ushort* __restrict__ WT,
                                                        int K, int F) {
  int i = blockIdx.x * 256 + threadIdx.x;
  if (i < K * F) {
    int k = i / F, f = i - k * F;
    WT[(size_t)f * K + k] = f2b(W[i]);
  }
}

// ---------------- MFMA GEMM: C[M,F] = A[M,K] * B[K,F], BT given as bf16 [F][K] ----------------
// block tile 128(M) x 128(N); 4 waves in 2x2, each 64x64 via 4x4 mfma_f32_16x16x32_bf16.
// A_F32: A is f32 (converted to bf16 during staging), else bf16(ushort).
// bias (f32, len F) added at store if non-null. OUT_F32 stores fp32, else bf16.
template<bool A_F32, bool OUT_F32>
__global__ __launch_bounds__(256) void gemm_bt(const void* __restrict__ Av,
                                               const ushort* __restrict__ BT,
                                               const float* __restrict__ bias,
                                               void* __restrict__ Cv,
                                               int M, int K, int F) {
  __shared__ ushort As[128 * 32];
  __shared__ ushort Bs[128 * 32];
  int tid = threadIdx.x;
  int lane = tid & 63;
  int wv = tid >> 6;
  int wm = (wv & 1) << 6;
  int wn = (wv >> 1) << 6;
  int bm = blockIdx.x << 7;
  int bn = blockIdx.y << 7;
  int lr = tid >> 2;           // 0..63 staging row
  int lc = (tid & 3) << 3;     // 0,8,16,24 staging col (elements)
  int q = lane >> 4, ml = lane & 15;

  floatx4 acc[4][4] = {};
  uint4 z4; z4.x = z4.y = z4.z = z4.w = 0u;

  for (int k0 = 0; k0 < K; k0 += 32) {
    int r0 = bm + lr, r1 = r0 + 64;
    uint4 a0, a1;
    if (A_F32) {
      const float* A = (const float*)Av;
      float f0[8] = {}, f1[8] = {};
      if (r0 < M) {
        *(float4*)&f0[0] = *(const float4*)(A + (size_t)r0 * K + k0 + lc);
        *(float4*)&f0[4] = *(const float4*)(A + (size_t)r0 * K + k0 + lc + 4);
      }
      if (r1 < M) {
        *(float4*)&f1[0] = *(const float4*)(A + (size_t)r1 * K + k0 + lc);
        *(float4*)&f1[4] = *(const float4*)(A + (size_t)r1 * K + k0 + lc + 4);
      }
      a0 = pack8(f0);
      a1 = pack8(f1);
    } else {
      const ushort* A = (const ushort*)Av;
      a0 = (r0 < M) ? *(const uint4*)(A + (size_t)r0 * K + k0 + lc) : z4;
      a1 = (r1 < M) ? *(const uint4*)(A + (size_t)r1 * K + k0 + lc) : z4;
    }
    int f0i = bn + lr, f1i = f0i + 64;
    uint4 b0 = (f0i < F) ? *(const uint4*)(BT + (size_t)f0i * K + k0 + lc) : z4;
    uint4 b1 = (f1i < F) ? *(const uint4*)(BT + (size_t)f1i * K + k0 + lc) : z4;
    __syncthreads();           // prior iter's LDS reads done
    *(uint4*)(As + lr * 32 + lc) = a0;
    *(uint4*)(As + (lr + 64) * 32 + lc) = a1;
    *(uint4*)(Bs + lr * 32 + lc) = b0;
    *(uint4*)(Bs + (lr + 64) * 32 + lc) = b1;
    __syncthreads();
    short8 af[4], bf[4];
#pragma unroll
    for (int i = 0; i < 4; i++)
      af[i] = *(const short8*)(As + (wm + 16 * i + ml) * 32 + q * 8);
#pragma unroll
    for (int j = 0; j < 4; j++)
      bf[j] = *(const short8*)(Bs + (wn + 16 * j + ml) * 32 + q * 8);
#pragma unroll
    for (int i = 0; i < 4; i++)
#pragma unroll
      for (int j = 0; j < 4; j++)
        acc[i][j] = __builtin_amdgcn_mfma_f32_16x16x32_bf16(af[i], bf[j], acc[i][j], 0, 0, 0);
  }

#pragma unroll
  for (int i = 0; i < 4; i++) {
#pragma unroll
    for (int j = 0; j < 4; j++) {
      int n = bn + wn + 16 * j + ml;      // C/D: col = lane&15  [m89 verified]
      if (n < F) {
        float bv = bias ? bias[n] : 0.0f;
#pragma unroll
        for (int r = 0; r < 4; r++) {
          int m = bm + wm + 16 * i + q * 4 + r;  // C/D: row = quad*4 + reg
          if (m < M) {
            float val = acc[i][j][r] + bv;
            if (OUT_F32) ((float*)Cv)[(size_t)m * F + n] = val;
            else         ((ushort*)Cv)[(size_t)m * F + n] = f2b(val);
          }
        }
      }
    }
  }
}

// ---------------- GCN aggregation: out[d] = relu(b + dinv_d^2*H[d] + sum_e dinv_s*dinv_d*H[s]) ----------------
// one wave per destination node; lane holds F/64 contiguous features. H bf16, out bf16, bias f32.
template<int F>
__global__ __launch_bounds__(256) void agg_kernel(const ushort* __restrict__ H,
                                                  const float* __restrict__ bias,
                                                  const float* __restrict__ dinv,
                                                  const int* __restrict__ rp,
                                                  const int* __restrict__ srcs,
                                                  ushort* __restrict__ out, int n) {
  constexpr int VPL = F / 64;
  int wid = blockIdx.x * 4 + (threadIdx.x >> 6);
  if (wid >= n) return;
  int lane = threadIdx.x & 63;
  int fo = lane * VPL;
  float invd = dinv[wid];
  float acc[VPL];
#pragma unroll
  for (int v = 0; v < VPL; v++) acc[v] = bias[fo + v];
  {
    float ws = invd * invd;
    const ushort* hp = H + (size_t)wid * F + fo;
    if (VPL == 4) {
      ushort4 hv = *(const ushort4*)hp;
      acc[0] += ws * b2f(hv.x); acc[1] += ws * b2f(hv.y);
      acc[2] += ws * b2f(hv.z); acc[3] += ws * b2f(hv.w);
    } else {
      ushort2 hv = *(const ushort2*)hp;
      acc[0] += ws * b2f(hv.x); acc[1] += ws * b2f(hv.y);
    }
  }
  int p = rp[wid], p1 = rp[wid + 1];
  int s = (p < p1) ? srcs[p] : 0;
  while (p < p1) {
    int sn = (p + 1 < p1) ? srcs[p + 1] : 0;   // prefetch next src index
    float w = dinv[s] * invd;
    const ushort* hp = H + (size_t)s * F + fo;
    if (VPL == 4) {
      ushort4 hv = *(const ushort4*)hp;
      acc[0] += w * b2f(hv.x); acc[1] += w * b2f(hv.y);
      acc[2] += w * b2f(hv.z); acc[3] += w * b2f(hv.w);
    } else {
      ushort2 hv = *(const ushort2*)hp;
      acc[0] += w * b2f(hv.x); acc[1] += w * b2f(hv.y);
    }
    s = sn; ++p;
  }
  ushort* op = out + (size_t)wid * F + fo;
#pragma unroll
  for (int v = 0; v < VPL; v++) op[v] = f2b(fmaxf(acc[v], 0.0f));
}

// ---------------- log_softmax over 64 classes: one wave per row, f32 in/out ----------------
__global__ __launch_bounds__(256) void logsoftmax_kernel(const float* __restrict__ logits,
                                                         float* __restrict__ out, int n) {
  int wid = blockIdx.x * 4 + (threadIdx.x >> 6);
  if (wid >= n) return;
  int lane = threadIdx.x & 63;
  float l = logits[(size_t)wid * 64 + lane];
  float m = l;
#pragma unroll
  for (int off = 32; off; off >>= 1) m = fmaxf(m, __shfl_xor(m, off, 64));
  float e = __expf(l - m);
#pragma unroll
  for (int off = 32; off; off >>= 1) e += __shfl_xor(e, off, 64);
  out[(size_t)wid * 64 + lane] = (l - m) - __logf(e);
}

// ---------------- launch ----------------

extern "C" void kernel_launch(void* const* d_in, const int* in_sizes, int n_in,
                              void* d_out, int out_size, void* d_ws, size_t ws_size,
                              hipStream_t stream) {
  const float* x  = (const float*)d_in[0];   // f32 per reference dtypes
  const int* ei   = (const int*)d_in[1];
  const float* W1 = (const float*)d_in[2];
  const float* b1 = (const float*)d_in[3];
  const float* W2 = (const float*)d_in[4];
  const float* b2 = (const float*)d_in[5];
  const float* Wc = (const float*)d_in[6];
  const float* bc = (const float*)d_in[7];

  const int N = in_sizes[0] / F_IN;
  const int E = in_sizes[1] / 2;
  const int* e_src = ei;
  const int* e_dst = ei + E;

  // workspace layout (256B aligned slices); total ~55.3 MB
  char* ws = (char*)d_ws;
  size_t off = 0;
  auto alloc = [&](size_t bytes) { char* p = ws + off; off += (bytes + 255) & ~(size_t)255; return p; };
  int*    cnt  = (int*)alloc((size_t)N * 4);
  float*  dinv = (float*)alloc((size_t)N * 4);
  int*    rp   = (int*)alloc((size_t)(N + 1) * 4);
  int*    srcs = (int*)alloc((size_t)E * 4);
  ushort* w1t  = (ushort*)alloc((size_t)F_HID * F_IN * 2);
  ushort* w2t  = (ushort*)alloc((size_t)F_MID * F_HID * 2);
  ushort* wct  = (ushort*)alloc((size_t)F_OUT * F_MID * 2);
  ushort* bufH = (ushort*)alloc((size_t)N * F_HID * 2);  // pre-agg H; reused as fp32 logits (N*64*4 == N*256 B <= N*512 B)
  ushort* bufG = (ushort*)alloc((size_t)N * F_HID * 2);  // post-agg h
  (void)ws_size; (void)n_in; (void)out_size;

  int gN = (N + 255) / 256, gE = (E + 255) / 256, gW = (N + 3) / 4, gM = (N + 127) / 128;

  // CSR + dinv
  zero_kernel<<<gN, 256, 0, stream>>>(cnt, N);
  hist_kernel<<<gE, 256, 0, stream>>>(e_dst, cnt, E);
  dinv_kernel<<<gN, 256, 0, stream>>>(cnt, dinv, N);
  scan_kernel<<<1, 1024, 0, stream>>>(cnt, rp, N);
  fill_kernel<<<gE, 256, 0, stream>>>(e_src, e_dst, rp, cnt, srcs, E);

  // weight transposes (f32 -> bf16 B^T layout)
  transpose_kernel<<<(F_IN * F_HID + 255) / 256, 256, 0, stream>>>(W1, w1t, F_IN, F_HID);
  transpose_kernel<<<(F_HID * F_MID + 255) / 256, 256, 0, stream>>>(W2, w2t, F_HID, F_MID);
  transpose_kernel<<<(F_MID * F_OUT + 255) / 256, 256, 0, stream>>>(Wc, wct, F_MID, F_OUT);

  // layer 1: H = x @ W1 (f32 A converted in staging) ; h1 = relu(agg(H) + b1)
  gemm_bt<true, false><<<dim3(gM, F_HID / 128), 256, 0, stream>>>(x, w1t, nullptr, bufH, N, F_IN, F_HID);
  agg_kernel<F_HID><<<gW, 256, 0, stream>>>(bufH, b1, dinv, rp, srcs, bufG, N);

  // layer 2: H2 = h1 @ W2 ; h2 = relu(agg(H2) + b2)
  gemm_bt<false, false><<<dim3(gM, 1), 256, 0, stream>>>(bufG, w2t, nullptr, bufH, N, F_HID, F_MID);
  agg_kernel<F_MID><<<gW, 256, 0, stream>>>(bufH, b2, dinv, rp, srcs, bufG, N);

  // classifier: logits = h2 @ Wc + bc (fp32, into bufH), then log_softmax -> d_out (f32)
  gemm_bt<false, true><<<dim3(gM, 1), 256, 0, stream>>>(bufG, wct, bc, (void*)bufH, N, F_MID, F_OUT);
  logsoftmax_kernel<<<gW, 256, 0, stream>>>((const float*)bufH, (float*)d_out, N);
}

// Round 3
// 445.761 us; speedup vs baseline: 1.3351x; 1.3351x over previous
//
#include <hip/hip_runtime.h>
#include <cstdint>
#include <cstddef>

// Problem constants (from reference): N=50000, E=800000, IN=512, HID=256, MID=128, OUT=64
#define F_IN  512
#define F_HID 256
#define F_MID 128
#define F_OUT 64

typedef __attribute__((ext_vector_type(8))) short short8;   // 8 x bf16 (4 VGPRs)
typedef __attribute__((ext_vector_type(4))) float floatx4;  // MFMA accumulator

static __device__ __forceinline__ float b2f(ushort u) {
  union { unsigned u; float f; } v; v.u = ((unsigned)u) << 16; return v.f;
}
static __device__ __forceinline__ ushort f2b(float f) {
  union { float f; unsigned u; } v; v.f = f;
  unsigned r = v.u + 0x7fffu + ((v.u >> 16) & 1u);  // round-to-nearest-even
  return (ushort)(r >> 16);
}
static __device__ __forceinline__ uint4 pack8(const float* f) {
  union { ushort u[8]; uint4 v; } r;
#pragma unroll
  for (int t = 0; t < 8; t++) r.u[t] = f2b(f[t]);
  return r.v;
}

// ---------------- CSR build ----------------

__global__ __launch_bounds__(256) void hist_kernel(const int* __restrict__ dst,
                                                   int* __restrict__ cnt, int e) {
  int i = blockIdx.x * 256 + threadIdx.x;
  if (i < e) atomicAdd(&cnt[dst[i]], 1);
}

__global__ __launch_bounds__(256) void dinv_kernel(const int* __restrict__ cnt,
                                                   float* __restrict__ dinv, int n) {
  int i = blockIdx.x * 256 + threadIdx.x;
  if (i < n) dinv[i] = rsqrtf(1.0f + (float)cnt[i]);  // deg includes self-loop
}

// hierarchical scan: (1) per-block exclusive scan + partial; zeroes cnt for cursor reuse
__global__ __launch_bounds__(1024) void scan1_kernel(int* __restrict__ cnt,
                                                     int* __restrict__ rp,
                                                     int* __restrict__ part, int n) {
  __shared__ int buf[1024];
  int tid = threadIdx.x;
  int i = blockIdx.x * 1024 + tid;
  int v = (i < n) ? cnt[i] : 0;
  buf[tid] = v;
  __syncthreads();
  for (int off = 1; off < 1024; off <<= 1) {
    int t = (tid >= off) ? buf[tid - off] : 0;
    __syncthreads();
    buf[tid] += t;
    __syncthreads();
  }
  if (i < n) { rp[i] = buf[tid] - v; cnt[i] = 0; }
  if (tid == 1023) part[blockIdx.x] = buf[1023];
}

// (2) scan of block partials (nb <= 1024), also writes rp[n] = total (== E)
__global__ __launch_bounds__(1024) void scan2_kernel(int* __restrict__ part,
                                                     int* __restrict__ rp, int nb, int n) {
  __shared__ int buf[1024];
  int tid = threadIdx.x;
  int v = (tid < nb) ? part[tid] : 0;
  buf[tid] = v;
  __syncthreads();
  for (int off = 1; off < 1024; off <<= 1) {
    int t = (tid >= off) ? buf[tid - off] : 0;
    __syncthreads();
    buf[tid] += t;
    __syncthreads();
  }
  if (tid < nb) part[tid] = buf[tid] - v;   // exclusive block offsets
  if (tid == nb - 1) rp[n] = buf[tid];      // total
}

// (3) add block offsets
__global__ __launch_bounds__(1024) void scan3_kernel(const int* __restrict__ part,
                                                     int* __restrict__ rp, int n) {
  int b = blockIdx.x;
  int i = b * 1024 + threadIdx.x;
  if (b > 0 && i < n) rp[i] += part[b];
}

__global__ __launch_bounds__(256) void fill_kernel(const int* __restrict__ src,
                                                   const int* __restrict__ dst,
                                                   const int* __restrict__ rp,
                                                   int* __restrict__ cur,
                                                   int* __restrict__ srcs, int e) {
  int i = blockIdx.x * 256 + threadIdx.x;
  if (i < e) {
    int d = dst[i];
    int p = rp[d] + atomicAdd(&cur[d], 1);
    srcs[p] = src[i];
  }
}

// W (f32, [K][F]) -> WT (bf16, [F][K])
__global__ __launch_bounds__(256) void transpose_kernel(const float* __restrict__ W,
                                                        ushort* __restrict__ WT,
                                                        int K, int F) {
  int i = blockIdx.x * 256 + threadIdx.x;
  if (i < K * F) {
    int k = i / F, f = i - k * F;
    WT[(size_t)f * K + k] = f2b(W[i]);
  }
}

// ---------------- MFMA GEMM: C[M,F] = A[M,K] * B[K,F], BT given as bf16 [F][K] ----------------
// block tile 128(M) x 128(N); 4 waves in 2x2, each 64x64 via 4x4 mfma_f32_16x16x32_bf16.
// A_F32: A is f32 (converted to bf16 during staging; ~4us device-wide VALU, negligible).
// bias (f32, len F) added at store if non-null. OUT_F32 stores fp32, else bf16.
template<bool A_F32, bool OUT_F32>
__global__ __launch_bounds__(256) void gemm_bt(const void* __restrict__ Av,
                                               const ushort* __restrict__ BT,
                                               const float* __restrict__ bias,
                                               void* __restrict__ Cv,
                                               int M, int K, int F) {
  __shared__ ushort As[128 * 32];
  __shared__ ushort Bs[128 * 32];
  int tid = threadIdx.x;
  int lane = tid & 63;
  int wv = tid >> 6;
  int wm = (wv & 1) << 6;
  int wn = (wv >> 1) << 6;
  int bm = blockIdx.x << 7;
  int bn = blockIdx.y << 7;
  int lr = tid >> 2;           // 0..63 staging row
  int lc = (tid & 3) << 3;     // 0,8,16,24 staging col (elements)
  int q = lane >> 4, ml = lane & 15;

  floatx4 acc[4][4] = {};
  uint4 z4; z4.x = z4.y = z4.z = z4.w = 0u;

  for (int k0 = 0; k0 < K; k0 += 32) {
    int r0 = bm + lr, r1 = r0 + 64;
    uint4 a0, a1;
    if (A_F32) {
      const float* A = (const float*)Av;
      float f0[8] = {}, f1[8] = {};
      if (r0 < M) {
        *(float4*)&f0[0] = *(const float4*)(A + (size_t)r0 * K + k0 + lc);
        *(float4*)&f0[4] = *(const float4*)(A + (size_t)r0 * K + k0 + lc + 4);
      }
      if (r1 < M) {
        *(float4*)&f1[0] = *(const float4*)(A + (size_t)r1 * K + k0 + lc);
        *(float4*)&f1[4] = *(const float4*)(A + (size_t)r1 * K + k0 + lc + 4);
      }
      a0 = pack8(f0);
      a1 = pack8(f1);
    } else {
      const ushort* A = (const ushort*)Av;
      a0 = (r0 < M) ? *(const uint4*)(A + (size_t)r0 * K + k0 + lc) : z4;
      a1 = (r1 < M) ? *(const uint4*)(A + (size_t)r1 * K + k0 + lc) : z4;
    }
    int f0i = bn + lr, f1i = f0i + 64;
    uint4 b0 = (f0i < F) ? *(const uint4*)(BT + (size_t)f0i * K + k0 + lc) : z4;
    uint4 b1 = (f1i < F) ? *(const uint4*)(BT + (size_t)f1i * K + k0 + lc) : z4;
    __syncthreads();           // prior iter's LDS reads done
    *(uint4*)(As + lr * 32 + lc) = a0;
    *(uint4*)(As + (lr + 64) * 32 + lc) = a1;
    *(uint4*)(Bs + lr * 32 + lc) = b0;
    *(uint4*)(Bs + (lr + 64) * 32 + lc) = b1;
    __syncthreads();
    short8 af[4], bf[4];
#pragma unroll
    for (int i = 0; i < 4; i++)
      af[i] = *(const short8*)(As + (wm + 16 * i + ml) * 32 + q * 8);
#pragma unroll
    for (int j = 0; j < 4; j++)
      bf[j] = *(const short8*)(Bs + (wn + 16 * j + ml) * 32 + q * 8);
#pragma unroll
    for (int i = 0; i < 4; i++)
#pragma unroll
      for (int j = 0; j < 4; j++)
        acc[i][j] = __builtin_amdgcn_mfma_f32_16x16x32_bf16(af[i], bf[j], acc[i][j], 0, 0, 0);
  }

#pragma unroll
  for (int i = 0; i < 4; i++) {
#pragma unroll
    for (int j = 0; j < 4; j++) {
      int n = bn + wn + 16 * j + ml;      // C/D: col = lane&15  [m89 verified]
      if (n < F) {
        float bv = bias ? bias[n] : 0.0f;
#pragma unroll
        for (int r = 0; r < 4; r++) {
          int m = bm + wm + 16 * i + q * 4 + r;  // C/D: row = quad*4 + reg
          if (m < M) {
            float val = acc[i][j][r] + bv;
            if (OUT_F32) ((float*)Cv)[(size_t)m * F + n] = val;
            else         ((ushort*)Cv)[(size_t)m * F + n] = f2b(val);
          }
        }
      }
    }
  }
}

// ---------------- GCN aggregation: out[d] = relu(b + dinv_d^2*H[d] + sum_e dinv_s*dinv_d*H[s]) ----------------
// one wave per destination node; lane holds F/64 contiguous features. H bf16, out bf16, bias f32.
// Edge loop unrolled x4: ~9 outstanding VMEM ops/wave for latency hiding (was ~2).
template<int F>
__global__ __launch_bounds__(256) void agg_kernel(const ushort* __restrict__ H,
                                                  const float* __restrict__ bias,
                                                  const float* __restrict__ dinv,
                                                  const int* __restrict__ rp,
                                                  const int* __restrict__ srcs,
                                                  ushort* __restrict__ out, int n) {
  constexpr int VPL = F / 64;
  int wid = blockIdx.x * 4 + (threadIdx.x >> 6);
  if (wid >= n) return;
  int lane = threadIdx.x & 63;
  int fo = lane * VPL;
  const ushort* Hf = H + fo;
  float invd = dinv[wid];
  float acc[VPL];
#pragma unroll
  for (int v = 0; v < VPL; v++) acc[v] = bias[fo + v];
  {
    float ws = invd * invd;
    if (VPL == 4) {
      ushort4 hv = *(const ushort4*)(Hf + (size_t)wid * F);
      acc[0] += ws * b2f(hv.x); acc[1] += ws * b2f(hv.y);
      acc[2] += ws * b2f(hv.z); acc[3] += ws * b2f(hv.w);
    } else {
      ushort2 hv = *(const ushort2*)(Hf + (size_t)wid * F);
      acc[0] += ws * b2f(hv.x); acc[1] += ws * b2f(hv.y);
    }
  }
  int p = rp[wid], p1 = rp[wid + 1];
  for (; p + 4 <= p1; p += 4) {
    int s0 = srcs[p], s1 = srcs[p + 1], s2 = srcs[p + 2], s3 = srcs[p + 3];
    float w0 = dinv[s0] * invd, w1 = dinv[s1] * invd,
          w2 = dinv[s2] * invd, w3 = dinv[s3] * invd;
    if (VPL == 4) {
      ushort4 h0 = *(const ushort4*)(Hf + (size_t)s0 * F);
      ushort4 h1 = *(const ushort4*)(Hf + (size_t)s1 * F);
      ushort4 h2 = *(const ushort4*)(Hf + (size_t)s2 * F);
      ushort4 h3 = *(const ushort4*)(Hf + (size_t)s3 * F);
      acc[0] += w0 * b2f(h0.x); acc[1] += w0 * b2f(h0.y);
      acc[2] += w0 * b2f(h0.z); acc[3] += w0 * b2f(h0.w);
      acc[0] += w1 * b2f(h1.x); acc[1] += w1 * b2f(h1.y);
      acc[2] += w1 * b2f(h1.z); acc[3] += w1 * b2f(h1.w);
      acc[0] += w2 * b2f(h2.x); acc[1] += w2 * b2f(h2.y);
      acc[2] += w2 * b2f(h2.z); acc[3] += w2 * b2f(h2.w);
      acc[0] += w3 * b2f(h3.x); acc[1] += w3 * b2f(h3.y);
      acc[2] += w3 * b2f(h3.z); acc[3] += w3 * b2f(h3.w);
    } else {
      ushort2 h0 = *(const ushort2*)(Hf + (size_t)s0 * F);
      ushort2 h1 = *(const ushort2*)(Hf + (size_t)s1 * F);
      ushort2 h2 = *(const ushort2*)(Hf + (size_t)s2 * F);
      ushort2 h3 = *(const ushort2*)(Hf + (size_t)s3 * F);
      acc[0] += w0 * b2f(h0.x); acc[1] += w0 * b2f(h0.y);
      acc[0] += w1 * b2f(h1.x); acc[1] += w1 * b2f(h1.y);
      acc[0] += w2 * b2f(h2.x); acc[1] += w2 * b2f(h2.y);
      acc[0] += w3 * b2f(h3.x); acc[1] += w3 * b2f(h3.y);
    }
  }
  for (; p < p1; ++p) {
    int s = srcs[p];
    float w = dinv[s] * invd;
    if (VPL == 4) {
      ushort4 hv = *(const ushort4*)(Hf + (size_t)s * F);
      acc[0] += w * b2f(hv.x); acc[1] += w * b2f(hv.y);
      acc[2] += w * b2f(hv.z); acc[3] += w * b2f(hv.w);
    } else {
      ushort2 hv = *(const ushort2*)(Hf + (size_t)s * F);
      acc[0] += w * b2f(hv.x); acc[1] += w * b2f(hv.y);
    }
  }
  ushort* op = out + (size_t)wid * F + fo;
#pragma unroll
  for (int v = 0; v < VPL; v++) op[v] = f2b(fmaxf(acc[v], 0.0f));
}

// ---------------- log_softmax over 64 classes: one wave per row, f32 in/out ----------------
__global__ __launch_bounds__(256) void logsoftmax_kernel(const float* __restrict__ logits,
                                                         float* __restrict__ out, int n) {
  int wid = blockIdx.x * 4 + (threadIdx.x >> 6);
  if (wid >= n) return;
  int lane = threadIdx.x & 63;
  float l = logits[(size_t)wid * 64 + lane];
  float m = l;
#pragma unroll
  for (int off = 32; off; off >>= 1) m = fmaxf(m, __shfl_xor(m, off, 64));
  float e = __expf(l - m);
#pragma unroll
  for (int off = 32; off; off >>= 1) e += __shfl_xor(e, off, 64);
  out[(size_t)wid * 64 + lane] = (l - m) - __logf(e);
}

// ---------------- launch ----------------

extern "C" void kernel_launch(void* const* d_in, const int* in_sizes, int n_in,
                              void* d_out, int out_size, void* d_ws, size_t ws_size,
                              hipStream_t stream) {
  const float* x  = (const float*)d_in[0];   // f32 per reference dtypes
  const int* ei   = (const int*)d_in[1];
  const float* W1 = (const float*)d_in[2];
  const float* b1 = (const float*)d_in[3];
  const float* W2 = (const float*)d_in[4];
  const float* b2 = (const float*)d_in[5];
  const float* Wc = (const float*)d_in[6];
  const float* bc = (const float*)d_in[7];

  const int N = in_sizes[0] / F_IN;
  const int E = in_sizes[1] / 2;
  const int* e_src = ei;
  const int* e_dst = ei + E;

  // workspace layout (256B aligned slices); total ~55.3 MB
  char* ws = (char*)d_ws;
  size_t off = 0;
  auto alloc = [&](size_t bytes) { char* p = ws + off; off += (bytes + 255) & ~(size_t)255; return p; };
  int*    cnt  = (int*)alloc((size_t)N * 4);
  float*  dinv = (float*)alloc((size_t)N * 4);
  int*    rp   = (int*)alloc((size_t)(N + 1) * 4);
  int*    part = (int*)alloc((size_t)1024 * 4);
  int*    srcs = (int*)alloc((size_t)E * 4);
  ushort* w1t  = (ushort*)alloc((size_t)F_HID * F_IN * 2);
  ushort* w2t  = (ushort*)alloc((size_t)F_MID * F_HID * 2);
  ushort* wct  = (ushort*)alloc((size_t)F_OUT * F_MID * 2);
  ushort* bufH = (ushort*)alloc((size_t)N * F_HID * 2);  // pre-agg H; reused as fp32 logits (N*64*4 == N*256 B <= N*512 B)
  ushort* bufG = (ushort*)alloc((size_t)N * F_HID * 2);  // post-agg h
  (void)ws_size; (void)n_in; (void)out_size;

  int gE = (E + 255) / 256, gW = (N + 3) / 4, gM = (N + 127) / 128;
  int nb = (N + 1023) / 1024;

  // CSR + dinv
  hipMemsetAsync(cnt, 0, (size_t)N * 4, stream);
  hist_kernel<<<gE, 256, 0, stream>>>(e_dst, cnt, E);
  dinv_kernel<<<(N + 255) / 256, 256, 0, stream>>>(cnt, dinv, N);
  scan1_kernel<<<nb, 1024, 0, stream>>>(cnt, rp, part, N);
  scan2_kernel<<<1, 1024, 0, stream>>>(part, rp, nb, N);
  scan3_kernel<<<nb, 1024, 0, stream>>>(part, rp, N);
  fill_kernel<<<gE, 256, 0, stream>>>(e_src, e_dst, rp, cnt, srcs, E);

  // weight transposes (f32 -> bf16 B^T layout)
  transpose_kernel<<<(F_IN * F_HID + 255) / 256, 256, 0, stream>>>(W1, w1t, F_IN, F_HID);
  transpose_kernel<<<(F_HID * F_MID + 255) / 256, 256, 0, stream>>>(W2, w2t, F_HID, F_MID);
  transpose_kernel<<<(F_MID * F_OUT + 255) / 256, 256, 0, stream>>>(Wc, wct, F_MID, F_OUT);

  // layer 1: H = x @ W1 (f32 A converted in staging) ; h1 = relu(agg(H) + b1)
  gemm_bt<true, false><<<dim3(gM, F_HID / 128), 256, 0, stream>>>(x, w1t, nullptr, bufH, N, F_IN, F_HID);
  agg_kernel<F_HID><<<gW, 256, 0, stream>>>(bufH, b1, dinv, rp, srcs, bufG, N);

  // layer 2: H2 = h1 @ W2 ; h2 = relu(agg(H2) + b2)
  gemm_bt<false, false><<<dim3(gM, 1), 256, 0, stream>>>(bufG, w2t, nullptr, bufH, N, F_HID, F_MID);
  agg_kernel<F_MID><<<gW, 256, 0, stream>>>(bufH, b2, dinv, rp, srcs, bufG, N);

  // classifier: logits = h2 @ Wc + bc (fp32, into bufH), then log_softmax -> d_out (f32)
  gemm_bt<false, true><<<dim3(gM, 1), 256, 0, stream>>>(bufG, wct, bc, (void*)bufH, N, F_MID, F_OUT);
  logsoftmax_kernel<<<gW, 256, 0, stream>>>((const float*)bufH, (float*)d_out, N);
}